// Round 9
// baseline (52.764 us; speedup 1.0000x reference)
//
#include <hip/hip_runtime.h>

// RoIAlign dense (11x11 bilinear) + 3x3/s2 max pool -> [K=2048, C=256, 5, 5]
// features: [B=4, C=256, H=100, W=100] f32 (NCHW), rois: [K,5] f32
//
// Ladder: R1 190us -> R2 45 (NHWC lane=channel) -> R5 42 main (static SGPR
// addressing, f32, VGPR 52) -> R6 66 main (bf16 pairs, store RMW blowup) ->
// R7 ~41 main (store fix, 12 waves/CU) -> R8 ~34 main (contiguous-half
// pairing, but ohi[25] regs -> ~80 VGPR -> capped at 16 waves/CU).
// R9: R5's 1-channel-per-lane shape + bf16 ushort loads. Pure-LDS stage
// (no reg-held outputs) -> VGPR ~55 (<=64 enforced) -> 24 waves/CU with
// margin. Loads are global_load_ushort (128 B/wave/tap, same total bytes
// as R8); unpack = 1 shift. Every 64B output line written once.

constexpr int Bn = 4, Cn = 256, Hn = 100, Wn = 100;
constexpr int HWn = Hn * Wn;
constexpr float SCALE = 0.0625f;

__device__ __forceinline__ unsigned int bfpack(float a, float b) {
    // RTNE f32->bf16, pack (a -> low16, b -> high16). Inputs finite.
    unsigned int ua = __float_as_uint(a), ub = __float_as_uint(b);
    ua = (ua + 0x7FFFu + ((ua >> 16) & 1u)) >> 16;
    ub = (ub + 0x7FFFu + ((ub >> 16) & 1u)) & 0xFFFF0000u;
    return ua | ub;
}

// ------- Kernel 1: NCHW f32 -> [B][HW][C] bf16 (ushort) transpose -------
__global__ __launch_bounds__(256)
void nchw_to_nhwc_bf16(const float* __restrict__ in, unsigned short* __restrict__ out)
{
    __shared__ float tile[64][65];           // [channel][spatial], +1 pad
    const int s0 = blockIdx.x * 64;
    const int c0 = blockIdx.y * 64;          // channel tile base
    const int b  = blockIdx.z;
    const int t  = threadIdx.x;

    {   // load: thread -> channel row, 4 consecutive spatial (dwordx4)
        const int cl = t >> 4;               // 0..15
        const int s4 = (t & 15) * 4;         // 0..60
        const float* ip = in + ((size_t)b * Cn + c0) * HWn + s0;
#pragma unroll
        for (int pass = 0; pass < 4; ++pass) {
            const int c = pass * 16 + cl;
            if (s0 + s4 + 3 < HWn) {
                const float4 v = *(const float4*)(ip + (size_t)c * HWn + s4);
                tile[c][s4 + 0] = v.x; tile[c][s4 + 1] = v.y;
                tile[c][s4 + 2] = v.z; tile[c][s4 + 3] = v.w;
            } else {
#pragma unroll
                for (int i = 0; i < 4; ++i)
                    tile[c][s4 + i] = (s0 + s4 + i < HWn) ? ip[(size_t)c * HWn + s4 + i] : 0.0f;
            }
        }
    }
    __syncthreads();
    {   // store: thread -> spatial s, 16 consecutive channels (2x uint4)
        const int s = t >> 2;                // 0..63
        const int q = t & 3;                 // 16-channel group
        if (s0 + s < HWn) {
            // u32 view of this spatial's channel row; c0 is 64-aligned,
            // q*16 channels = q*8 dwords -> 16B-aligned uint4 stores.
            unsigned int* op = (unsigned int*)(out + ((size_t)b * HWn + (s0 + s)) * Cn + c0);
            const int cb = q * 16;           // local channel base
#pragma unroll
            for (int h = 0; h < 2; ++h) {
                uint4 v;
                v.x = bfpack(tile[cb + h * 8 + 0][s], tile[cb + h * 8 + 1][s]);
                v.y = bfpack(tile[cb + h * 8 + 2][s], tile[cb + h * 8 + 3][s]);
                v.z = bfpack(tile[cb + h * 8 + 4][s], tile[cb + h * 8 + 5][s]);
                v.w = bfpack(tile[cb + h * 8 + 6][s], tile[cb + h * 8 + 7][s]);
                *(uint4*)(op + q * 8 + h * 4) = v;
            }
        }
    }
}

// ------------- Kernel 2: RoIAlign+pool, lane = channel, bf16 loads -------------
// 256-thr block = 1 roi, wave wid covers channels wid*64..+63.
__global__ __launch_bounds__(256, 8)
void roipool_bf16(const unsigned short* __restrict__ f, const float* __restrict__ rois,
                  float* __restrict__ out)
{
    __shared__ float stage[4][1600];          // [wave][64ch x 25] = 25.6 KB
    const int tid  = threadIdx.x;
    const int wid  = tid >> 6;
    const int lane = tid & 63;
    const int k    = blockIdx.x;

    const float x1 = rois[k * 5 + 1] * SCALE;
    const float y1 = rois[k * 5 + 2] * SCALE;
    const float x2 = rois[k * 5 + 3] * SCALE;
    const float y2 = rois[k * 5 + 4] * SCALE;
    const int   b  = __builtin_amdgcn_readfirstlane((int)rois[k * 5 + 0]);

    const int ch = wid * 64 + lane;           // per-lane channel (only VGPR in addr)
    const unsigned short* fb = f + (size_t)b * HWn * Cn;   // uniform base

    // per-roi x-tap metadata: element offsets as SGPRs, weights per-lane
    int   xo0[11], xo1[11];
    float wx[11];
#pragma unroll
    for (int j = 0; j < 11; ++j) {
        const float xs  = x1 + (x2 - x1) * ((float)j * 0.1f);
        const float x0f = floorf(xs);
        wx[j] = xs - x0f;                     // weight from UNCLIPPED coord
        const int x0i = (int)x0f;
        xo0[j] = __builtin_amdgcn_readfirstlane(min(max(x0i,     0), Wn - 1)) * Cn;
        xo1[j] = __builtin_amdgcn_readfirstlane(min(max(x0i + 1, 0), Wn - 1)) * Cn;
    }

    // one dense sample row gy -> 5 x-window maxes; fully static, no branches
    auto dorow = [&](int gy, float (&dst)[5]) {
        const float ys  = y1 + (y2 - y1) * ((float)gy * 0.1f);
        const float y0f = floorf(ys);
        const float wy  = ys - y0f;
        const int   y0i = (int)y0f;
        const int r0 = __builtin_amdgcn_readfirstlane(min(max(y0i,     0), Hn - 1));
        const int r1 = __builtin_amdgcn_readfirstlane(min(max(y0i + 1, 0), Hn - 1));
        const unsigned short* rp0 = fb + (size_t)(r0 * Wn) * Cn;  // uniform row ptrs
        const unsigned short* rp1 = fb + (size_t)(r1 * Wn) * Cn;
        float s[11];
#pragma unroll
        for (int j = 0; j < 11; ++j) {
            const unsigned int u00 = (rp0 + xo0[j])[ch];   // uniform ptr + lane idx
            const unsigned int u01 = (rp0 + xo1[j])[ch];
            const unsigned int u10 = (rp1 + xo0[j])[ch];
            const unsigned int u11 = (rp1 + xo1[j])[ch];
            const float t00 = __uint_as_float(u00 << 16);  // bf16 -> f32 = shl
            const float t01 = __uint_as_float(u01 << 16);
            const float t10 = __uint_as_float(u10 << 16);
            const float t11 = __uint_as_float(u11 << 16);
            const float X0 = t00 + wx[j] * (t01 - t00);
            const float X1 = t10 + wx[j] * (t11 - t10);
            s[j] = X0 + wy * (X1 - X0);
        }
        dst[0] = fmaxf(fmaxf(s[0], s[1]), s[2]);
        dst[1] = fmaxf(fmaxf(s[2], s[3]), s[4]);
        dst[2] = fmaxf(fmaxf(s[4], s[5]), s[6]);
        dst[3] = fmaxf(fmaxf(s[6], s[7]), s[8]);
        dst[4] = fmaxf(fmaxf(s[8], s[9]), s[10]);
    };

    float xp_prev[5];
    dorow(0, xp_prev);
    float* stw = stage[wid];
    float* stl = &stw[lane * 25];
#pragma unroll
    for (int ph = 0; ph < 5; ++ph) {
        float t[5], nxt[5];
        dorow(2 * ph + 1, t);
        dorow(2 * ph + 2, nxt);
#pragma unroll
        for (int pw = 0; pw < 5; ++pw) {
            stl[ph * 5 + pw] = fmaxf(fmaxf(xp_prev[pw], t[pw]), nxt[pw]);
            xp_prev[pw]      = nxt[pw];
        }
    }

    // same-wave LDS in-order; pin compiler ordering before the copy-out
    asm volatile("" ::: "memory");

    // single coalesced copy: this wave's 64 channels are contiguous 1600 floats
    float* ob = out + (size_t)k * (Cn * 25) + (size_t)wid * 1600;
#pragma unroll
    for (int i = 0; i < 25; ++i)
        ob[i * 64 + lane] = stw[i * 64 + lane];
}

// ------------- Fallback (reads NCHW directly) if workspace too small -------------
__global__ __launch_bounds__(256)
void roialign_pool_fallback(const float* __restrict__ feats,
                            const float* __restrict__ rois,
                            float* __restrict__ out)
{
    __shared__ float smem[4][2][128];
    const int k    = blockIdx.x;
    const int tid  = threadIdx.x;
    const int wid  = tid >> 6;
    const int lane = tid & 63;

    const float x1 = rois[k * 5 + 1] * SCALE;
    const float y1 = rois[k * 5 + 2] * SCALE;
    const float x2 = rois[k * 5 + 3] * SCALE;
    const float y2 = rois[k * 5 + 4] * SCALE;
    const int   b  = (int)rois[k * 5 + 0];

    const int  p1   = 64 + lane;
    const bool act1 = (p1 < 121);
    int   o00[2], o01[2], o10[2], o11[2];
    float w00[2], w01[2], w10[2], w11[2];
#pragma unroll
    for (int r = 0; r < 2; ++r) {
        const int p  = (r == 0) ? lane : (act1 ? p1 : 120);
        const int gy = p / 11;
        const int gx = p - gy * 11;
        const float ys = y1 + (y2 - y1) * ((float)gy / 10.0f);
        const float xs = x1 + (x2 - x1) * ((float)gx / 10.0f);
        const float y0f = floorf(ys), x0f = floorf(xs);
        const float wy = ys - y0f, wxx = xs - x0f;
        const int y0i = (int)y0f, x0i = (int)x0f;
        const int y0c = min(max(y0i, 0), Hn - 1), y1c = min(max(y0i + 1, 0), Hn - 1);
        const int x0c = min(max(x0i, 0), Wn - 1), x1c = min(max(x0i + 1, 0), Wn - 1);
        o00[r] = y0c * Wn + x0c; o01[r] = y0c * Wn + x1c;
        o10[r] = y1c * Wn + x0c; o11[r] = y1c * Wn + x1c;
        w00[r] = (1.0f - wy) * (1.0f - wxx); w01[r] = (1.0f - wy) * wxx;
        w10[r] = wy * (1.0f - wxx);          w11[r] = wy * wxx;
    }
    const bool pool  = (lane < 25);
    const int  ph    = lane / 5;
    const int  pw    = lane - ph * 5;
    const int  pbase = (2 * ph) * 11 + 2 * pw;
    const float* base = feats + ((size_t)b * Cn + (size_t)wid * 64) * HWn;
    float*       op   = out + ((size_t)k * Cn + (size_t)wid * 64) * 25 + lane;
    for (int it = 0; it < 64; ++it) {
        const float* ff  = base + (size_t)it * HWn;
        float*       buf = smem[wid][it & 1];
        const float v0 = ff[o00[0]] * w00[0] + ff[o01[0]] * w01[0]
                       + ff[o10[0]] * w10[0] + ff[o11[0]] * w11[0];
        const float v1 = ff[o00[1]] * w00[1] + ff[o01[1]] * w01[1]
                       + ff[o10[1]] * w10[1] + ff[o11[1]] * w11[1];
        buf[lane] = v0;
        if (act1) buf[p1] = v1;
        if (pool) {
            float m =          buf[pbase +  0];
            m = fmaxf(m, buf[pbase +  1]);
            m = fmaxf(m, buf[pbase +  2]);
            m = fmaxf(m, buf[pbase + 11]);
            m = fmaxf(m, buf[pbase + 12]);
            m = fmaxf(m, buf[pbase + 13]);
            m = fmaxf(m, buf[pbase + 22]);
            m = fmaxf(m, buf[pbase + 23]);
            m = fmaxf(m, buf[pbase + 24]);
            op[it * 25] = m;
        }
    }
}

extern "C" void kernel_launch(void* const* d_in, const int* in_sizes, int n_in,
                              void* d_out, int out_size, void* d_ws, size_t ws_size,
                              hipStream_t stream) {
    const float* feats = (const float*)d_in[0];
    const float* rois  = (const float*)d_in[1];
    float*       out   = (float*)d_out;
    const int K = in_sizes[1] / 5;                                   // 2048
    const size_t need = (size_t)Bn * HWn * Cn * sizeof(unsigned short);  // 20.48 MB

    if (ws_size >= need) {
        unsigned short* nhwc = (unsigned short*)d_ws;
        dim3 tgrid((HWn + 63) / 64, Cn / 64, Bn);                    // 157 x 4 x 4
        nchw_to_nhwc_bf16<<<tgrid, 256, 0, stream>>>(feats, nhwc);
        roipool_bf16<<<K, 256, 0, stream>>>(nhwc, rois, out);
    } else {
        roialign_pool_fallback<<<K, 256, 0, stream>>>(feats, rois, out);
    }
}